// Round 11
// baseline (260.323 us; speedup 1.0000x reference)
//
#include <hip/hip_runtime.h>
#include <stdint.h>
#include <math.h>

typedef unsigned short u16;
typedef __attribute__((ext_vector_type(8))) short short8;   // 8 x bf16 (4 VGPRs)
typedef __attribute__((ext_vector_type(4))) float f32x4;    // MFMA acc
typedef __attribute__((ext_vector_type(4))) unsigned short u16x4;
typedef __attribute__((ext_vector_type(2))) unsigned int uint2v;

#define DEV static __device__ __forceinline__

DEV u16 f2bf(float f) {
    unsigned u = __builtin_bit_cast(unsigned, f);
    u = u + 0x7fffu + ((u >> 16) & 1u);   // RNE
    return (u16)(u >> 16);
}
DEV float bf2f(u16 s) { return __builtin_bit_cast(float, ((unsigned)s) << 16); }
DEV float fexp2(float x) {
#if __has_builtin(__builtin_amdgcn_exp2f)
    return __builtin_amdgcn_exp2f(x);
#else
    return __expf(x * 0.69314718056f);
#endif
}
// two f32 -> packed 2xbf16 in one VALU op (RNE); replaces 5-op integer pk2
DEV unsigned cvtpk(float a, float b) {
    unsigned w;
    asm("v_cvt_pk_bf16_f32 %0, %1, %2" : "=v"(w) : "v"(a), "v"(b));
    return w;
}
// T1: XCD-aware chunked block swizzle (bijective when nwg % 8 == 0).
DEV int xcd_swz(int flat, int nwg) {
    int cpx = nwg >> 3;
    return (flat & 7) * cpx + (flat >> 3);
}

// async 16B global -> LDS (wave-uniform dest base + lane*16)
DEV void gl_lds16(const u16* g, u16* l) {
#if __has_builtin(__builtin_amdgcn_global_load_lds)
    __builtin_amdgcn_global_load_lds((const __attribute__((address_space(1))) unsigned int*)g,
                                     (__attribute__((address_space(3))) unsigned int*)l, 16, 0, 0);
#else
    *(short8*)l = *(const short8*)g;
#endif
}

// barrier WITHOUT the vmcnt drain (T4-lite): lgkm only — ds_writes visible, VGPR-destined
// global prefetch loads stay in flight across the barrier.
DEV void barrier_lgkm() {
    asm volatile("s_waitcnt lgkmcnt(0)" ::: "memory");
    __builtin_amdgcn_sched_barrier(0);
    __builtin_amdgcn_s_barrier();
}

// B=2, N=2048, D=1024, H=16, HD=64

// ---------------- adaLN stage 1 (fp32, silu fused, 8-way K-split via atomics) ----------------
__global__ __launch_bounds__(256) void k_ada1(const float* __restrict__ emb, const float* __restrict__ W,
                                              float* __restrict__ out) {
    int col = blockIdx.x * 64 + (threadIdx.x & 63);
    int b = blockIdx.y;
    int kbase = blockIdx.z * 128 + (threadIdx.x >> 6) * 32;
    float acc = 0.f;
    for (int k = kbase; k < kbase + 32; k++) {
        float e = emb[b * 1024 + k];
        float se = e / (1.f + __expf(-e));
        acc += se * W[(size_t)k * 1024 + col];
    }
    __shared__ float red[4][64];
    red[threadIdx.x >> 6][threadIdx.x & 63] = acc;
    __syncthreads();
    if (threadIdx.x < 64)
        atomicAdd(out + b * 1024 + blockIdx.x * 64 + threadIdx.x,
                  red[0][threadIdx.x] + red[1][threadIdx.x] + red[2][threadIdx.x] + red[3][threadIdx.x]);
}

// ---------------- prep: z<6 weight conv (0..3 transposed, 4..5 plain); z==6 ada2 (atomic ksplit); z==7 sincos ----
__global__ __launch_bounds__(256) void k_prep(const float* s0, u16* d0, const float* s1, u16* d1,
                                              const float* s2, u16* d2, const float* s3, u16* d3,
                                              const float* s4, u16* d4, const float* s5, u16* d5,
                                              const float* __restrict__ t_ada, const float* __restrict__ Wada2,
                                              float* __restrict__ ada, const float* __restrict__ rope,
                                              float* __restrict__ cst, float* __restrict__ snt) {
    __shared__ u16 tile[64][65];
    __shared__ float red[4][64];
    if (blockIdx.z == 6) {
        int flat = blockIdx.y * 16 + blockIdx.x;       // 0..255
        int kq = flat >> 6;                            // 4-way K-split
        int rest = flat & 63;
        int b = rest >> 5, xb = rest & 31;
        int col = xb * 64 + (threadIdx.x & 63);
        int kbase = kq * 256 + (threadIdx.x >> 6) * 64;
        float acc = 0.f;
        for (int k = kbase; k < kbase + 64; k++)
            acc += t_ada[b * 1024 + k] * Wada2[(size_t)k * 2048 + col];
        red[threadIdx.x >> 6][threadIdx.x & 63] = acc;
        __syncthreads();
        if (threadIdx.x < 64)
            atomicAdd(ada + b * 2048 + xb * 64 + threadIdx.x,
                      red[0][threadIdx.x] + red[1][threadIdx.x] + red[2][threadIdx.x] + red[3][threadIdx.x]);
        return;
    }
    if (blockIdx.z == 7) {
        int flat = blockIdx.y * 16 + blockIdx.x;
        if (flat < 128) {
            int idx = flat * 1024 + threadIdx.x * 4;   // 131072 = 2048*64
            float4 rv = *(const float4*)(rope + idx);
            float4 cv, sv;
            __sincosf(rv.x, &sv.x, &cv.x);
            __sincosf(rv.y, &sv.y, &cv.y);
            __sincosf(rv.z, &sv.z, &cv.z);
            __sincosf(rv.w, &sv.w, &cv.w);
            *(float4*)(cst + idx) = cv;
            *(float4*)(snt + idx) = sv;
        }
        return;
    }
    const float* s; u16* d;
    switch (blockIdx.z) {
        case 0: s = s0; d = d0; break;
        case 1: s = s1; d = d1; break;
        case 2: s = s2; d = d2; break;
        case 3: s = s3; d = d3; break;
        case 4: s = s4; d = d4; break;
        default: s = s5; d = d5; break;
    }
    int k0 = blockIdx.x * 64, n0 = blockIdx.y * 64;
    int tx = threadIdx.x & 63, ty = threadIdx.x >> 6;
    if (blockIdx.z >= 4) {
        #pragma unroll
        for (int i = 0; i < 16; i++) {
            int kk = ty + 4 * i;
            d[(size_t)(k0 + kk) * 1024 + n0 + tx] = f2bf(s[(size_t)(k0 + kk) * 1024 + n0 + tx]);
        }
        return;
    }
    #pragma unroll
    for (int i = 0; i < 16; i++) {
        int kk = ty + 4 * i;
        tile[kk][tx] = f2bf(s[(size_t)(k0 + kk) * 1024 + n0 + tx]);
    }
    __syncthreads();
    #pragma unroll
    for (int i = 0; i < 16; i++) {
        int nn = ty + 4 * i;
        d[(size_t)(n0 + nn) * 1024 + k0 + tx] = tile[tx][nn];
    }
}

// ---------------- bf16 MFMA GEMM core: BK=32, TRIPLE-buffered LDS, counted-vmcnt pipeline ----
template <int BM, int BN, int MODE>
DEV void gemm_core(const u16* __restrict__ A, const u16* __restrict__ Bt,
                   u16* __restrict__ Cb, float* __restrict__ Cf, u16* __restrict__ Vt,
                   const float* __restrict__ Xres, const float* __restrict__ gate,
                   const float* __restrict__ cst, const float* __restrict__ snt,
                   float scale, int Nn, int K, int m0, int n0) {
    constexpr int MI = BM / 32, NJ = BN / 32;
    constexpr int PA = BM / 64, PB = BN / 64;
    constexpr int LA = BM * 32, LB = BN * 32;          // u16 elems per operand per buffer
    constexpr int LBUF = LA + LB;
    constexpr int SST = 3 * LBUF;
    constexpr int SM = (MODE == 2 && BM * 132 > SST) ? BM * 132 : SST;
    __shared__ u16 smem[SM];
    int tid = threadIdx.x;
    int lane = tid & 63, wave = tid >> 6;
    int wm = (wave & 1) * (BM / 2), wn = (wave >> 1) * (BN / 2);
    int lr = lane & 15, quad = lane >> 4;
    f32x4 acc[MI][NJ];
    #pragma unroll
    for (int i = 0; i < MI; i++)
        #pragma unroll
        for (int j = 0; j < NJ; j++) acc[i][j] = f32x4{0.f, 0.f, 0.f, 0.f};

    int arow = tid >> 2;                 // 4 threads/row, 64 rows/pass
    int achunk = (tid & 3) * 8;          // 16B chunk within 32-col tile
    const u16* ap = A + (size_t)(m0 + arow) * K + achunk;
    const u16* bp = Bt + (size_t)(n0 + arow) * K + achunk;

    // stage tile `it` (32 cols at koff=it*32) into buffer d — pure DMA
    auto stage = [&](int it, int d) {
        int koff = it * 32;
        int ab = d * LBUF, bb = d * LBUF + LA;
        #pragma unroll
        for (int p = 0; p < PA; p++)
            gl_lds16(ap + koff + (size_t)(64 * p) * K, smem + ab + (arow + 64 * p) * 32 + achunk);
        #pragma unroll
        for (int p = 0; p < PB; p++)
            gl_lds16(bp + koff + (size_t)(64 * p) * K, smem + bb + (arow + 64 * p) * 32 + achunk);
    };

    stage(0, 0);
    stage(1, 1);
    asm volatile("s_waitcnt vmcnt(%0)" :: "i"(PA + PB) : "memory");   // tile0 landed; tile1 in flight
    __builtin_amdgcn_sched_barrier(0);
    __builtin_amdgcn_s_barrier();
    #pragma unroll 1
    for (int it = 0; it < 32; ++it) {
        int cur = it % 3;
        if (it + 2 < 32) stage(it + 2, (it + 2) % 3);   // flies across the barrier below
        int ab = cur * LBUF, bb = ab + LA;
        short8 af[MI], bfr[NJ];
        #pragma unroll
        for (int i = 0; i < MI; i++)
            af[i] = *(const short8*)(smem + ab + (wm + i * 16 + lr) * 32 + quad * 8);
        #pragma unroll
        for (int j = 0; j < NJ; j++)
            bfr[j] = *(const short8*)(smem + bb + (wn + j * 16 + lr) * 32 + quad * 8);
        #pragma unroll
        for (int i = 0; i < MI; i++)
            #pragma unroll
            for (int j = 0; j < NJ; j++)
                acc[i][j] = __builtin_amdgcn_mfma_f32_16x16x32_bf16(af[i], bfr[j], acc[i][j], 0, 0, 0);
        if (it + 1 < 32) {
            if (it + 2 < 32)
                asm volatile("s_waitcnt vmcnt(%0)" :: "i"(PA + PB) : "memory");  // tile it+1 done
            else
                asm volatile("s_waitcnt vmcnt(0)" ::: "memory");                 // tail: tile 31 done
            __builtin_amdgcn_sched_barrier(0);
            __builtin_amdgcn_s_barrier();
        }
    }
    __syncthreads();   // final lane sync (all DMA retired) before epilogue smem reuse

    if (MODE == 2) {
        if ((n0 + wn) < 2048) {
            // rope on q/k columns: wave spans exactly one 64-wide head block
            #pragma unroll
            for (int i = 0; i < MI; i++)
                #pragma unroll
                for (int jp = 0; jp < 2; jp++)
                    #pragma unroll
                    for (int r = 0; r < 4; r++) {
                        int row = m0 + wm + i * 16 + quad * 4 + r;
                        int n = row & 2047;
                        int d1 = jp * 16 + lr;
                        float c1 = cst[n * 64 + d1],      s1 = snt[n * 64 + d1];
                        float c2 = cst[n * 64 + d1 + 32], s2 = snt[n * 64 + d1 + 32];
                        float x1 = acc[i][jp][r], x2 = acc[i][jp + 2][r];
                        Cb[(size_t)row * Nn + n0 + wn + d1]      = f2bf(x1 * c1 - x2 * s1);
                        Cb[(size_t)row * Nn + n0 + wn + d1 + 32] = f2bf(x2 * c2 + x1 * s2);
                    }
        } else {
            // v columns: LDS transpose (reuse freed smem) then coalesced 16B row stores to vt
            #pragma unroll
            for (int i = 0; i < MI; i++)
                #pragma unroll
                for (int j = 0; j < NJ; j++) {
                    u16x4 w;
                    w.x = f2bf(acc[i][j][0]); w.y = f2bf(acc[i][j][1]);
                    w.z = f2bf(acc[i][j][2]); w.w = f2bf(acc[i][j][3]);
                    *(u16x4*)(&smem[(wn + j * 16 + lr) * 132 + wm + i * 16 + quad * 4]) = w;
                }
            __syncthreads();
            int d = tid >> 1, half = tid & 1;
            int gcol = n0 - 2048 + d;
            int hv = gcol >> 6, dl = gcol & 63;
            int bb2 = m0 >> 11;
            int nloc = (m0 & 2047) + half * 64;
            u16* dst = Vt + ((size_t)((bb2 * 16 + hv) * 64 + dl)) * 2048 + nloc;
            #pragma unroll
            for (int c = 0; c < 8; c++)
                *(short8*)(dst + c * 8) = *(const short8*)(&smem[d * 132 + half * 64 + c * 8]);
        }
        return;
    }
    #pragma unroll
    for (int i = 0; i < MI; i++)
        #pragma unroll
        for (int j = 0; j < NJ; j++)
            #pragma unroll
            for (int r = 0; r < 4; r++) {
                int row = m0 + wm + i * 16 + quad * 4 + r;
                int col = n0 + wn + j * 16 + lr;
                float v = acc[i][j][r];
                if (MODE == 1) {
                    int b = row >> 11;
                    Cf[(size_t)row * Nn + col] = Xres[(size_t)row * Nn + col] + gate[b * 1024 + col] * v;
                } else {
                    Cb[(size_t)row * Nn + col] = f2bf(v * scale);
                }
            }
}

template <int BM, int BN, int MODE, int WPE>
__global__ __launch_bounds__(256, WPE) void gemm_bt(const u16* __restrict__ A, const u16* __restrict__ Bt,
                                                    u16* __restrict__ Cb, float* __restrict__ Cf,
                                                    u16* __restrict__ Vt,
                                                    const float* __restrict__ Xres, const float* __restrict__ gate,
                                                    const float* __restrict__ cst, const float* __restrict__ snt,
                                                    int Nn, int K) {
    // T1: XCD-chunked swizzle (nwg % 8 == 0 for all instantiations: 768, 1024)
    int gx = gridDim.x;
    int flat = blockIdx.y * gx + blockIdx.x;
    int swz = xcd_swz(flat, gx * gridDim.y);
    gemm_core<BM, BN, MODE>(A, Bt, Cb, Cf, Vt, Xres, gate, cst, snt, 1.f, Nn, K,
                            (swz / gx) * BM, (swz % gx) * BN);
}

// ---------------- fold (2x 1024^3 GEMM, blocks 0..255) + LayerNorm (blocks 256..4351) ----------
// R11: merged launch — ln's 4096 light BW-bound blocks backfill CU wave-slots while the 256
// heavy fold blocks run (fold was ~1 block/CU: most of the machine idle). Saves ln's serial
// time + one dispatch gap. Both paths only need k_prep outputs, so ordering is preserved.
__global__ __launch_bounds__(256) void k_foldln(const u16* A0, const u16* B0, u16* C0,
                                                const u16* A1, const u16* B1, u16* C1,
                                                const float* __restrict__ x, const float* __restrict__ ada,
                                                const float* __restrict__ bada2, u16* __restrict__ xn) {
    int fid = blockIdx.x;
    if (fid < 256) {
        // fold: two independent 1024^3 folds, 128x64 tiles; q-fold scale = 0.125/ln2
        int z = fid >> 7, flat = fid & 127;
        int swz = xcd_swz(flat, 128);
        const u16* A = z ? A1 : A0;
        const u16* Bt = z ? B1 : B0;
        u16* C = z ? C1 : C0;
        float scale = z ? 1.0f : 0.18033688f;
        gemm_core<128, 64, 0>(A, Bt, C, nullptr, nullptr, nullptr, nullptr, nullptr, nullptr, scale,
                              1024, 1024, (swz >> 4) * 128, (swz & 15) * 64);
        return;
    }
    // LayerNorm + adaLN modulate (ada2 bias folded here) -> bf16
    int row = fid - 256;
    int b = row >> 11;
    float4 v = ((const float4*)(x + (size_t)row * 1024))[threadIdx.x];
    float s = v.x + v.y + v.z + v.w;
    float ss = v.x * v.x + v.y * v.y + v.z * v.z + v.w * v.w;
    #pragma unroll
    for (int m = 1; m < 64; m <<= 1) { s += __shfl_xor(s, m, 64); ss += __shfl_xor(ss, m, 64); }
    __shared__ float red[2][4];
    int wave = threadIdx.x >> 6, lane = threadIdx.x & 63;
    if (lane == 0) { red[0][wave] = s; red[1][wave] = ss; }
    __syncthreads();
    s = red[0][0] + red[0][1] + red[0][2] + red[0][3];
    ss = red[1][0] + red[1][1] + red[1][2] + red[1][3];
    float mu = s * (1.f / 1024.f);
    float var = ss * (1.f / 1024.f) - mu * mu;
    float rs = rsqrtf(var + 1e-6f);
    int c = threadIdx.x * 4;
    const float* sh = ada + b * 2048;
    const float* sc = ada + b * 2048 + 1024;
    u16x4 r;
    r.x = f2bf((v.x - mu) * rs * (1.f + sc[c + 0] + bada2[1024 + c + 0]) + sh[c + 0] + bada2[c + 0]);
    r.y = f2bf((v.y - mu) * rs * (1.f + sc[c + 1] + bada2[1024 + c + 1]) + sh[c + 1] + bada2[c + 1]);
    r.z = f2bf((v.z - mu) * rs * (1.f + sc[c + 2] + bada2[1024 + c + 2]) + sh[c + 2] + bada2[c + 2]);
    r.w = f2bf((v.w - mu) * rs * (1.f + sc[c + 3] + bada2[1024 + c + 3]) + sh[c + 3] + bada2[c + 3]);
    *(u16x4*)(xn + (size_t)row * 1024 + c) = r;
}

// ---------------- flash attention: BQ=128, BK=64, 8 waves (stable 50.4us config) ----------------
__global__ __launch_bounds__(512) void k_attn(const u16* __restrict__ qkv, const u16* __restrict__ vt,
                                              u16* __restrict__ aob) {
    __shared__ u16 pool[128 * 72];       // Qs view: stride 64 (staged); Pt view: stride 72 (wave-private)
    __shared__ u16 Ks[2][64][64];
    __shared__ u16 Vs[2][64][64];
    int flat = blockIdx.y * 16 + blockIdx.x;           // 512 blocks
    int swz = xcd_swz(flat, 512);
    int q0 = (swz & 15) * 128;
    int bh = swz >> 4; int b = bh >> 4, h = bh & 15;
    int tid = threadIdx.x;
    int lane = tid & 63, wave = tid >> 6;          // 8 waves
    int lr = lane & 15, quad = lane >> 4;
    int srow = tid >> 3, scol = (tid & 7) * 8;     // srow 0..63: full K/V tile, 1 short8/thread
    int sg = (((tid & 7) ^ (srow & 7))) * 8;
    int cc[2] = { ((quad ^ (lr & 7))) * 8, (((4 + quad) ^ (lr & 7))) * 8 };
    int qrow = wave * 16 + lr;                     // this lane's q-row (0..127)

    const u16* kp = qkv + ((size_t)(b * 2048 + srow)) * 2048 + 1024 + h * 64 + sg;
    const u16* vp = vt + ((size_t)(bh * 64 + srow)) * 2048 + sg;

    // Q staging (DMA; drained at first barrier): 512 thr x 16B = 8KB/shot, 2 shots
    #pragma unroll
    for (int p = 0; p < 2; p++)
        gl_lds16(qkv + ((size_t)(b * 2048 + q0 + srow + 64 * p)) * 2048 + h * 64 + sg,
                 pool + (srow + 64 * p) * 64 + scol);

    short8 krA, vrA, krB, vrB;
    krA = *(const short8*)(kp);
    vrA = *(const short8*)(vp);
    __syncthreads();                             // Q (and t0 regs) ready — full drain
    short8 qf[2];
    #pragma unroll
    for (int ks = 0; ks < 2; ks++)
        qf[ks] = *(const short8*)(pool + qrow * 64 + cc[ks]);
    // t0 -> LDS[0]; t1 -> regs B
    *(short8*)(&Ks[0][srow][scol]) = krA;
    *(short8*)(&Vs[0][srow][scol]) = vrA;
    krB = *(const short8*)(kp + (size_t)64 * 2048);
    vrB = *(const short8*)(vp + 64);
    __syncthreads();

    float l_part = 0.f;
    f32x4 oacc[4];
    #pragma unroll
    for (int dt = 0; dt < 4; dt++) oacc[dt] = f32x4{0.f, 0.f, 0.f, 0.f};

    auto body = [&](int it, int cur, short8& krF, short8& vrF, short8& krH, short8& vrH) {
        if (it < 30) {   // prefetch t(it+2) into the freed reg slot — survives the lgkm barrier
            krF = *(const short8*)(kp + (size_t)(it + 2) * 64 * 2048);
            vrF = *(const short8*)(vp + (it + 2) * 64);
        }
        // S^T[key][qrow] = mfma(A=K, B=Q)
        f32x4 st[4];
        #pragma unroll
        for (int ct = 0; ct < 4; ct++) st[ct] = f32x4{0.f, 0.f, 0.f, 0.f};
        #pragma unroll
        for (int ks = 0; ks < 2; ks++) {
            short8 kf[4];
            #pragma unroll
            for (int ct = 0; ct < 4; ct++)
                kf[ct] = *(const short8*)(&Ks[cur][ct * 16 + lr][cc[ks]]);
            __builtin_amdgcn_s_setprio(1);
            #pragma unroll
            for (int ct = 0; ct < 4; ct++)
                st[ct] = __builtin_amdgcn_mfma_f32_16x16x32_bf16(kf[ct], qf[ks], st[ct], 0, 0, 0);
            __builtin_amdgcn_s_setprio(0);
        }
        // p = exp2(s); per-lane row sums; packed b64 P-store, Pt[qrow][key] (wave-private)
        #pragma unroll
        for (int ct = 0; ct < 4; ct++) {
            float p0 = fexp2(st[ct][0]);
            float p1 = fexp2(st[ct][1]);
            float p2 = fexp2(st[ct][2]);
            float p3 = fexp2(st[ct][3]);
            l_part += (p0 + p1) + (p2 + p3);
            uint2v w; w.x = cvtpk(p0, p1); w.y = cvtpk(p2, p3);
            *(uint2v*)(pool + qrow * 72 + ct * 16 + quad * 4) = w;
        }
        // O += P V
        #pragma unroll
        for (int ks = 0; ks < 2; ks++) {
            short8 pf, vf[4];
            pf = *(const short8*)(pool + qrow * 72 + ks * 32 + quad * 8);
            #pragma unroll
            for (int dt = 0; dt < 4; dt++)
                vf[dt] = *(const short8*)(&Vs[cur][dt * 16 + lr][cc[ks]]);
            __builtin_amdgcn_s_setprio(1);
            #pragma unroll
            for (int dt = 0; dt < 4; dt++)
                oacc[dt] = __builtin_amdgcn_mfma_f32_16x16x32_bf16(pf, vf[dt], oacc[dt], 0, 0, 0);
            __builtin_amdgcn_s_setprio(0);
        }
        // hand tile t(it+1) to the next LDS buffer (compiler inserts this wave's vmcnt wait)
        if (it < 31) {
            int nxt = cur ^ 1;
            *(short8*)(&Ks[nxt][srow][scol]) = krH;
            *(short8*)(&Vs[nxt][srow][scol]) = vrH;
        }
        barrier_lgkm();   // ds_writes visible; global prefetch stays in flight
    };

    #pragma unroll 1
    for (int it2 = 0; it2 < 16; ++it2) {
        body(2 * it2,     0, krA, vrA, krB, vrB);
        body(2 * it2 + 1, 1, krB, vrB, krA, vrA);
    }

    // full-row l (replicated across quads after xor-reduce); fetch l for row quad*4+r via shfl
    float l = l_part;
    l += __shfl_xor(l, 16, 64);
    l += __shfl_xor(l, 32, 64);
    float linv[4];
    #pragma unroll
    for (int r = 0; r < 4; r++)
        linv[r] = 1.f / __shfl(l, quad * 4 + r, 64);
    // normalized bf16 O, direct aob store (row = q-row, col = h*64 + dt*16 + lr)
    #pragma unroll
    for (int dt = 0; dt < 4; dt++)
        #pragma unroll
        for (int r = 0; r < 4; r++) {
            int row = q0 + wave * 16 + quad * 4 + r;
            aob[((size_t)(b * 2048 + row)) * 1024 + h * 64 + dt * 16 + lr] =
                f2bf(oacc[dt][r] * linv[r]);
        }
}

// ---------------- launch ----------------
extern "C" void kernel_launch(void* const* d_in, const int* in_sizes, int n_in,
                              void* d_out, int out_size, void* d_ws, size_t ws_size,
                              hipStream_t stream) {
    const float* x     = (const float*)d_in[0];
    const float* emb   = (const float*)d_in[1];
    const float* gate  = (const float*)d_in[2];
    // d_in[3] crossattn_emb: unused by the reference
    const float* rope  = (const float*)d_in[4];
    const float* Wq1   = (const float*)d_in[5];
    const float* Wq2   = (const float*)d_in[6];
    const float* Wk1   = (const float*)d_in[7];
    const float* Wk2   = (const float*)d_in[8];
    const float* Wv    = (const float*)d_in[9];
    const float* Wo    = (const float*)d_in[10];
    const float* Wada1 = (const float*)d_in[11];
    const float* Wada2 = (const float*)d_in[12];
    const float* bada2 = (const float*)d_in[13];
    float* out = (float*)d_out;

    char* ws = (char*)d_ws;
    size_t off = 0;
    auto alloc = [&](size_t bytes) { void* p = ws + off; off += (bytes + 255) & ~(size_t)255; return p; };
    float* t_ada = (float*)alloc(2048 * 4);              // 8192 B
    float* ada   = (float*)alloc(4096 * 4);              // contiguous after t_ada (16384 B)
    float* cst   = (float*)alloc((size_t)131072 * 4);
    float* snt   = (float*)alloc((size_t)131072 * 4);
    u16* xn    = (u16*)alloc((size_t)4096 * 1024 * 2);
    u16* Wq1b  = (u16*)alloc((size_t)1024 * 1024 * 2);
    u16* Wk1b  = (u16*)alloc((size_t)1024 * 1024 * 2);
    u16* Wq2t  = (u16*)alloc((size_t)1024 * 1024 * 2);
    u16* Wk2t  = (u16*)alloc((size_t)1024 * 1024 * 2);
    u16* Wot   = (u16*)alloc((size_t)1024 * 1024 * 2);
    u16* WqkvT = (u16*)alloc((size_t)3072 * 1024 * 2);   // rows: WqeT | WkeT | WvT
    u16* qkvb  = (u16*)alloc((size_t)4096 * 2048 * 2);   // q|k (roped), row stride 2048
    u16* vtb   = (u16*)alloc((size_t)4096 * 1024 * 2);   // vt[bh][d][n]
    u16* aob   = (u16*)alloc((size_t)4096 * 1024 * 2);
    (void)ws_size; (void)in_sizes; (void)n_in; (void)out_size;

    // zero both atomic K-split targets in ONE memset (t_ada+ada are contiguous: 8192+16384)
    hipMemsetAsync(t_ada, 0, 24576, stream);

    // adaLN stage 1 (widened, atomics)
    k_ada1<<<dim3(16, 2, 8), 256, 0, stream>>>(emb, Wada1, t_ada);

    // prep: weight conversions + ada2 (atomics) + rope tables
    k_prep<<<dim3(16, 16, 8), 256, 0, stream>>>(Wq2, Wq2t, Wk2, Wk2t,
                                                Wv, WqkvT + (size_t)2048 * 1024, Wo, Wot,
                                                Wq1, Wq1b, Wk1, Wk1b,
                                                t_ada, Wada2, ada, rope, cst, snt);

    // fold (256 heavy blocks) + LayerNorm (4096 light blocks) in one launch — ln backfills CUs
    k_foldln<<<4352, 256, 0, stream>>>(Wq2t, Wq1b, WqkvT,
                                       Wk2t, Wk1b, WqkvT + (size_t)1024 * 1024,
                                       x, ada, bada2, xn);

    // fused QKV projection + rope epilogue + LDS-transposed V store (counted-vmcnt pipeline)
    gemm_bt<128, 128, 2, 4><<<dim3(24, 32), 256, 0, stream>>>(xn, WqkvT, qkvb, nullptr, vtb,
                                                              nullptr, nullptr, cst, snt, 2048, 1024);

    // flash attention: single launch, XCD-swizzled, lgkm-only body barrier
    k_attn<<<dim3(16, 32), 512, 0, stream>>>(qkvb, vtb, aob);

    // final projection + gated residual: 64x64 tiles -> 1024 blocks (~4-6/CU, latency hedge)
    gemm_bt<64, 64, 1, 4><<<dim3(16, 64), 256, 0, stream>>>(aob, Wot, nullptr, out, nullptr, x, gate,
                                                            nullptr, nullptr, 1024, 1024);
}

// Round 12
// 255.871 us; speedup vs baseline: 1.0174x; 1.0174x over previous
//
#include <hip/hip_runtime.h>
#include <stdint.h>
#include <math.h>

typedef unsigned short u16;
typedef __attribute__((ext_vector_type(8))) short short8;   // 8 x bf16 (4 VGPRs)
typedef __attribute__((ext_vector_type(4))) float f32x4;    // MFMA acc
typedef __attribute__((ext_vector_type(4))) unsigned short u16x4;
typedef __attribute__((ext_vector_type(2))) unsigned int uint2v;

#define DEV static __device__ __forceinline__

DEV u16 f2bf(float f) {
    unsigned u = __builtin_bit_cast(unsigned, f);
    u = u + 0x7fffu + ((u >> 16) & 1u);   // RNE
    return (u16)(u >> 16);
}
DEV float bf2f(u16 s) { return __builtin_bit_cast(float, ((unsigned)s) << 16); }
DEV float fexp2(float x) {
#if __has_builtin(__builtin_amdgcn_exp2f)
    return __builtin_amdgcn_exp2f(x);
#else
    return __expf(x * 0.69314718056f);
#endif
}
// two f32 -> packed 2xbf16 in one VALU op (RNE)
DEV unsigned cvtpk(float a, float b) {
    unsigned w;
    asm("v_cvt_pk_bf16_f32 %0, %1, %2" : "=v"(w) : "v"(a), "v"(b));
    return w;
}
// T1: XCD-aware chunked block swizzle (bijective when nwg % 8 == 0).
DEV int xcd_swz(int flat, int nwg) {
    int cpx = nwg >> 3;
    return (flat & 7) * cpx + (flat >> 3);
}

// async 16B global -> LDS (wave-uniform dest base + lane*16)
DEV void gl_lds16(const u16* g, u16* l) {
#if __has_builtin(__builtin_amdgcn_global_load_lds)
    __builtin_amdgcn_global_load_lds((const __attribute__((address_space(1))) unsigned int*)g,
                                     (__attribute__((address_space(3))) unsigned int*)l, 16, 0, 0);
#else
    *(short8*)l = *(const short8*)g;
#endif
}

// barrier WITHOUT the vmcnt drain (attn only): lgkm only.
DEV void barrier_lgkm() {
    asm volatile("s_waitcnt lgkmcnt(0)" ::: "memory");
    __builtin_amdgcn_sched_barrier(0);
    __builtin_amdgcn_s_barrier();
}

// B=2, N=2048, D=1024, H=16, HD=64

// ---------------- adaLN stage 1 (fp32, silu fused, 8-way K-split via atomics) ----------------
__global__ __launch_bounds__(256) void k_ada1(const float* __restrict__ emb, const float* __restrict__ W,
                                              float* __restrict__ out) {
    int col = blockIdx.x * 64 + (threadIdx.x & 63);
    int b = blockIdx.y;
    int kbase = blockIdx.z * 128 + (threadIdx.x >> 6) * 32;
    float acc = 0.f;
    for (int k = kbase; k < kbase + 32; k++) {
        float e = emb[b * 1024 + k];
        float se = e / (1.f + __expf(-e));
        acc += se * W[(size_t)k * 1024 + col];
    }
    __shared__ float red[4][64];
    red[threadIdx.x >> 6][threadIdx.x & 63] = acc;
    __syncthreads();
    if (threadIdx.x < 64)
        atomicAdd(out + b * 1024 + blockIdx.x * 64 + threadIdx.x,
                  red[0][threadIdx.x] + red[1][threadIdx.x] + red[2][threadIdx.x] + red[3][threadIdx.x]);
}

// ---------------- prep: z<6 weight conv (0..3 transposed, 4..5 plain); z==6 ada2 (atomic ksplit); z==7 sincos ----
__global__ __launch_bounds__(256) void k_prep(const float* s0, u16* d0, const float* s1, u16* d1,
                                              const float* s2, u16* d2, const float* s3, u16* d3,
                                              const float* s4, u16* d4, const float* s5, u16* d5,
                                              const float* __restrict__ t_ada, const float* __restrict__ Wada2,
                                              float* __restrict__ ada, const float* __restrict__ rope,
                                              float* __restrict__ cst, float* __restrict__ snt) {
    __shared__ u16 tile[64][65];
    __shared__ float red[4][64];
    if (blockIdx.z == 6) {
        int flat = blockIdx.y * 16 + blockIdx.x;       // 0..255
        int kq = flat >> 6;                            // 4-way K-split
        int rest = flat & 63;
        int b = rest >> 5, xb = rest & 31;
        int col = xb * 64 + (threadIdx.x & 63);
        int kbase = kq * 256 + (threadIdx.x >> 6) * 64;
        float acc = 0.f;
        for (int k = kbase; k < kbase + 64; k++)
            acc += t_ada[b * 1024 + k] * Wada2[(size_t)k * 2048 + col];
        red[threadIdx.x >> 6][threadIdx.x & 63] = acc;
        __syncthreads();
        if (threadIdx.x < 64)
            atomicAdd(ada + b * 2048 + xb * 64 + threadIdx.x,
                      red[0][threadIdx.x] + red[1][threadIdx.x] + red[2][threadIdx.x] + red[3][threadIdx.x]);
        return;
    }
    if (blockIdx.z == 7) {
        int flat = blockIdx.y * 16 + blockIdx.x;
        if (flat < 128) {
            int idx = flat * 1024 + threadIdx.x * 4;   // 131072 = 2048*64
            float4 rv = *(const float4*)(rope + idx);
            float4 cv, sv;
            __sincosf(rv.x, &sv.x, &cv.x);
            __sincosf(rv.y, &sv.y, &cv.y);
            __sincosf(rv.z, &sv.z, &cv.z);
            __sincosf(rv.w, &sv.w, &cv.w);
            *(float4*)(cst + idx) = cv;
            *(float4*)(snt + idx) = sv;
        }
        return;
    }
    const float* s; u16* d;
    switch (blockIdx.z) {
        case 0: s = s0; d = d0; break;
        case 1: s = s1; d = d1; break;
        case 2: s = s2; d = d2; break;
        case 3: s = s3; d = d3; break;
        case 4: s = s4; d = d4; break;
        default: s = s5; d = d5; break;
    }
    int k0 = blockIdx.x * 64, n0 = blockIdx.y * 64;
    int tx = threadIdx.x & 63, ty = threadIdx.x >> 6;
    if (blockIdx.z >= 4) {
        #pragma unroll
        for (int i = 0; i < 16; i++) {
            int kk = ty + 4 * i;
            d[(size_t)(k0 + kk) * 1024 + n0 + tx] = f2bf(s[(size_t)(k0 + kk) * 1024 + n0 + tx]);
        }
        return;
    }
    #pragma unroll
    for (int i = 0; i < 16; i++) {
        int kk = ty + 4 * i;
        tile[kk][tx] = f2bf(s[(size_t)(k0 + kk) * 1024 + n0 + tx]);
    }
    __syncthreads();
    #pragma unroll
    for (int i = 0; i < 16; i++) {
        int nn = ty + 4 * i;
        d[(size_t)(n0 + nn) * 1024 + k0 + tx] = tile[tx][nn];
    }
}

// ---------------- LayerNorm + adaLN modulate (ada2 bias folded here) -> bf16 ----------------
__global__ __launch_bounds__(256) void k_ln(const float* __restrict__ x, const float* __restrict__ ada,
                                            const float* __restrict__ bada2, u16* __restrict__ xn) {
    int row = blockIdx.x;
    int b = row >> 11;
    float4 v = ((const float4*)(x + (size_t)row * 1024))[threadIdx.x];
    float s = v.x + v.y + v.z + v.w;
    float ss = v.x * v.x + v.y * v.y + v.z * v.z + v.w * v.w;
    #pragma unroll
    for (int m = 1; m < 64; m <<= 1) { s += __shfl_xor(s, m, 64); ss += __shfl_xor(ss, m, 64); }
    __shared__ float red[2][4];
    int wave = threadIdx.x >> 6, lane = threadIdx.x & 63;
    if (lane == 0) { red[0][wave] = s; red[1][wave] = ss; }
    __syncthreads();
    s = red[0][0] + red[0][1] + red[0][2] + red[0][3];
    ss = red[1][0] + red[1][1] + red[1][2] + red[1][3];
    float mu = s * (1.f / 1024.f);
    float var = ss * (1.f / 1024.f) - mu * mu;
    float rs = rsqrtf(var + 1e-6f);
    int c = threadIdx.x * 4;
    const float* sh = ada + b * 2048;
    const float* sc = ada + b * 2048 + 1024;
    u16x4 r;
    r.x = f2bf((v.x - mu) * rs * (1.f + sc[c + 0] + bada2[1024 + c + 0]) + sh[c + 0] + bada2[c + 0]);
    r.y = f2bf((v.y - mu) * rs * (1.f + sc[c + 1] + bada2[1024 + c + 1]) + sh[c + 1] + bada2[c + 1]);
    r.z = f2bf((v.z - mu) * rs * (1.f + sc[c + 2] + bada2[1024 + c + 2]) + sh[c + 2] + bada2[c + 2]);
    r.w = f2bf((v.w - mu) * rs * (1.f + sc[c + 3] + bada2[1024 + c + 3]) + sh[c + 3] + bada2[c + 3]);
    *(u16x4*)(xn + (size_t)row * 1024 + c) = r;
}

// ---------------- bf16 MFMA GEMM core: 512 THREADS (8 waves, 4M x 2N), BK=32, dbuf drain ----
// R12: the GEMMs are TLP-starved (QKV: MfmaUtil 21 / VALU 14 / HBM 15 / Occ 26 — all idle;
// per-K-step 1.42us == m97's characteristic rate). 8 waves/block doubles waves/CU at identical
// tiles/LDS/data-movement. Wave-grid 4M x 2N keeps rope epilogue's full-64-wide head ownership.
// Staging: 512 thr x 16B = one full 128x32 operand tile per shot; LDS dest = base + tid*16 (DMA ok).
template <int BM, int BN, int MODE>
DEV void gemm_core(const u16* __restrict__ A, const u16* __restrict__ Bt,
                   u16* __restrict__ Cb, float* __restrict__ Cf, u16* __restrict__ Vt,
                   const float* __restrict__ Xres, const float* __restrict__ gate,
                   const float* __restrict__ cst, const float* __restrict__ snt,
                   float scale, int Nn, int K, int m0, int n0) {
    constexpr int MI = BM / 64, NJ = BN / 32;          // per-wave frag counts
    constexpr int LA = BM * 32, LB = BN * 32;          // u16 elems per operand per buffer
    constexpr int LBUF = LA + LB;
    constexpr int SST = 2 * LBUF;
    constexpr int SM = (MODE == 2 && BM * 132 > SST) ? BM * 132 : SST;
    __shared__ u16 smem[SM];
    int tid = threadIdx.x;
    int lane = tid & 63, wave = tid >> 6;              // 8 waves
    int wm = (wave & 3) * (BM / 4), wn = (wave >> 2) * (BN / 2);
    int lr = lane & 15, quad = lane >> 4;
    f32x4 acc[MI][NJ];
    #pragma unroll
    for (int i = 0; i < MI; i++)
        #pragma unroll
        for (int j = 0; j < NJ; j++) acc[i][j] = f32x4{0.f, 0.f, 0.f, 0.f};

    int arow = tid >> 2;                 // 4 threads/row: 512 thr cover 128 rows in one pass
    int achunk = (tid & 3) * 8;          // 16B chunk within 32-col tile
    const u16* ap = A + (size_t)(m0 + arow) * K + achunk;
    const u16* bp = Bt + (size_t)(n0 + arow) * K + achunk;

    // stage tile `it` into buffer d — pure DMA; B guarded when BN < 128 (wave-uniform branch)
    auto stage = [&](int it, int d) {
        int koff = it * 32;
        int ab = d * LBUF, bb = d * LBUF + LA;
        if (tid < BM * 4)
            gl_lds16(ap + koff, smem + ab + arow * 32 + achunk);
        if (tid < BN * 4)
            gl_lds16(bp + koff, smem + bb + arow * 32 + achunk);
    };

    stage(0, 0);
    __syncthreads();                     // tile 0 ready
    #pragma unroll 1
    for (int it = 0; it < 32; ++it) {
        int cur = it & 1;
        if (it + 1 < 32) stage(it + 1, cur ^ 1);   // lands by this iteration's closing barrier
        int ab = cur * LBUF, bb = ab + LA;
        short8 af[MI], bfr[NJ];
        #pragma unroll
        for (int i = 0; i < MI; i++)
            af[i] = *(const short8*)(smem + ab + (wm + i * 16 + lr) * 32 + quad * 8);
        #pragma unroll
        for (int j = 0; j < NJ; j++)
            bfr[j] = *(const short8*)(smem + bb + (wn + j * 16 + lr) * 32 + quad * 8);
        #pragma unroll
        for (int i = 0; i < MI; i++)
            #pragma unroll
            for (int j = 0; j < NJ; j++)
                acc[i][j] = __builtin_amdgcn_mfma_f32_16x16x32_bf16(af[i], bfr[j], acc[i][j], 0, 0, 0);
        __syncthreads();                 // drains staging DMA + guards buffer reuse
    }

    if (MODE == 2) {
        if ((n0 + wn) < 2048) {
            // rope on q/k columns: wave owns a full 64-wide head block (wn in {0,64})
            #pragma unroll
            for (int i = 0; i < MI; i++)
                #pragma unroll
                for (int jp = 0; jp < 2; jp++)
                    #pragma unroll
                    for (int r = 0; r < 4; r++) {
                        int row = m0 + wm + i * 16 + quad * 4 + r;
                        int n = row & 2047;
                        int d1 = jp * 16 + lr;
                        float c1 = cst[n * 64 + d1],      s1 = snt[n * 64 + d1];
                        float c2 = cst[n * 64 + d1 + 32], s2 = snt[n * 64 + d1 + 32];
                        float x1 = acc[i][jp][r], x2 = acc[i][jp + 2][r];
                        Cb[(size_t)row * Nn + n0 + wn + d1]      = f2bf(x1 * c1 - x2 * s1);
                        Cb[(size_t)row * Nn + n0 + wn + d1 + 32] = f2bf(x2 * c2 + x1 * s2);
                    }
        } else {
            // v columns: LDS transpose (reuse freed smem) then coalesced vt stores
            #pragma unroll
            for (int i = 0; i < MI; i++)
                #pragma unroll
                for (int j = 0; j < NJ; j++) {
                    u16x4 w;
                    w.x = f2bf(acc[i][j][0]); w.y = f2bf(acc[i][j][1]);
                    w.z = f2bf(acc[i][j][2]); w.w = f2bf(acc[i][j][3]);
                    *(u16x4*)(&smem[(wn + j * 16 + lr) * 132 + wm + i * 16 + quad * 4]) = w;
                }
            __syncthreads();
            int d = tid >> 2, q4 = tid & 3;            // 512 thr: 128 d-rows x 4 n-quarters
            int gcol = n0 - 2048 + d;
            int hv = gcol >> 6, dl = gcol & 63;
            int bb2 = m0 >> 11;
            int nloc = (m0 & 2047) + q4 * 32;
            u16* dst = Vt + ((size_t)((bb2 * 16 + hv) * 64 + dl)) * 2048 + nloc;
            #pragma unroll
            for (int c = 0; c < 4; c++)
                *(short8*)(dst + c * 8) = *(const short8*)(&smem[d * 132 + q4 * 32 + c * 8]);
        }
        return;
    }
    #pragma unroll
    for (int i = 0; i < MI; i++)
        #pragma unroll
        for (int j = 0; j < NJ; j++)
            #pragma unroll
            for (int r = 0; r < 4; r++) {
                int row = m0 + wm + i * 16 + quad * 4 + r;
                int col = n0 + wn + j * 16 + lr;
                float v = acc[i][j][r];
                if (MODE == 1) {
                    int b = row >> 11;
                    Cf[(size_t)row * Nn + col] = Xres[(size_t)row * Nn + col] + gate[b * 1024 + col] * v;
                } else {
                    Cb[(size_t)row * Nn + col] = f2bf(v * scale);
                }
            }
}

template <int BM, int BN, int MODE, int WPE>
__global__ __launch_bounds__(512, WPE) void gemm_bt(const u16* __restrict__ A, const u16* __restrict__ Bt,
                                                    u16* __restrict__ Cb, float* __restrict__ Cf,
                                                    u16* __restrict__ Vt,
                                                    const float* __restrict__ Xres, const float* __restrict__ gate,
                                                    const float* __restrict__ cst, const float* __restrict__ snt,
                                                    int Nn, int K) {
    // T1: XCD-chunked swizzle (nwg % 8 == 0 for all instantiations: 768, 512)
    int gx = gridDim.x;
    int flat = blockIdx.y * gx + blockIdx.x;
    int swz = xcd_swz(flat, gx * gridDim.y);
    gemm_core<BM, BN, MODE>(A, Bt, Cb, Cf, Vt, Xres, gate, cst, snt, 1.f, Nn, K,
                            (swz / gx) * BM, (swz % gx) * BN);
}

// two independent 1024^3 folds (z selects), 128x64 tiles; q-fold scale = 0.125/ln2
__global__ __launch_bounds__(512, 4) void gemm_fold(const u16* A0, const u16* B0, u16* C0,
                                                    const u16* A1, const u16* B1, u16* C1) {
    const u16* A = blockIdx.z ? A1 : A0;
    const u16* Bt = blockIdx.z ? B1 : B0;
    u16* C = blockIdx.z ? C1 : C0;
    float scale = blockIdx.z ? 1.0f : 0.18033688f;
    int flat = blockIdx.y * 16 + blockIdx.x;           // 128 blocks per z
    int swz = xcd_swz(flat, 128);
    gemm_core<128, 64, 0>(A, Bt, C, nullptr, nullptr, nullptr, nullptr, nullptr, nullptr, scale,
                          1024, 1024, (swz >> 4) * 128, (swz & 15) * 64);
}

// ---------------- flash attention: BQ=128, BK=64, 8 waves (stable 50.0-50.8us config) ----------
__global__ __launch_bounds__(512) void k_attn(const u16* __restrict__ qkv, const u16* __restrict__ vt,
                                              u16* __restrict__ aob) {
    __shared__ u16 pool[128 * 72];       // Qs view: stride 64 (staged); Pt view: stride 72 (wave-private)
    __shared__ u16 Ks[2][64][64];
    __shared__ u16 Vs[2][64][64];
    int flat = blockIdx.y * 16 + blockIdx.x;           // 512 blocks
    int swz = xcd_swz(flat, 512);
    int q0 = (swz & 15) * 128;
    int bh = swz >> 4; int b = bh >> 4, h = bh & 15;
    int tid = threadIdx.x;
    int lane = tid & 63, wave = tid >> 6;          // 8 waves
    int lr = lane & 15, quad = lane >> 4;
    int srow = tid >> 3, scol = (tid & 7) * 8;     // srow 0..63: full K/V tile, 1 short8/thread
    int sg = (((tid & 7) ^ (srow & 7))) * 8;
    int cc[2] = { ((quad ^ (lr & 7))) * 8, (((4 + quad) ^ (lr & 7))) * 8 };
    int qrow = wave * 16 + lr;                     // this lane's q-row (0..127)

    const u16* kp = qkv + ((size_t)(b * 2048 + srow)) * 2048 + 1024 + h * 64 + sg;
    const u16* vp = vt + ((size_t)(bh * 64 + srow)) * 2048 + sg;

    // Q staging (DMA; drained at first barrier): 512 thr x 16B = 8KB/shot, 2 shots
    #pragma unroll
    for (int p = 0; p < 2; p++)
        gl_lds16(qkv + ((size_t)(b * 2048 + q0 + srow + 64 * p)) * 2048 + h * 64 + sg,
                 pool + (srow + 64 * p) * 64 + scol);

    short8 krA, vrA, krB, vrB;
    krA = *(const short8*)(kp);
    vrA = *(const short8*)(vp);
    __syncthreads();                             // Q (and t0 regs) ready — full drain
    short8 qf[2];
    #pragma unroll
    for (int ks = 0; ks < 2; ks++)
        qf[ks] = *(const short8*)(pool + qrow * 64 + cc[ks]);
    // t0 -> LDS[0]; t1 -> regs B
    *(short8*)(&Ks[0][srow][scol]) = krA;
    *(short8*)(&Vs[0][srow][scol]) = vrA;
    krB = *(const short8*)(kp + (size_t)64 * 2048);
    vrB = *(const short8*)(vp + 64);
    __syncthreads();

    float l_part = 0.f;
    f32x4 oacc[4];
    #pragma unroll
    for (int dt = 0; dt < 4; dt++) oacc[dt] = f32x4{0.f, 0.f, 0.f, 0.f};

    auto body = [&](int it, int cur, short8& krF, short8& vrF, short8& krH, short8& vrH) {
        if (it < 30) {   // prefetch t(it+2) into the freed reg slot — survives the lgkm barrier
            krF = *(const short8*)(kp + (size_t)(it + 2) * 64 * 2048);
            vrF = *(const short8*)(vp + (it + 2) * 64);
        }
        // S^T[key][qrow] = mfma(A=K, B=Q)
        f32x4 st[4];
        #pragma unroll
        for (int ct = 0; ct < 4; ct++) st[ct] = f32x4{0.f, 0.f, 0.f, 0.f};
        #pragma unroll
        for (int ks = 0; ks < 2; ks++) {
            short8 kf[4];
            #pragma unroll
            for (int ct = 0; ct < 4; ct++)
                kf[ct] = *(const short8*)(&Ks[cur][ct * 16 + lr][cc[ks]]);
            __builtin_amdgcn_s_setprio(1);
            #pragma unroll
            for (int ct = 0; ct < 4; ct++)
                st[ct] = __builtin_amdgcn_mfma_f32_16x16x32_bf16(kf[ct], qf[ks], st[ct], 0, 0, 0);
            __builtin_amdgcn_s_setprio(0);
        }
        // p = exp2(s); per-lane row sums; packed b64 P-store, Pt[qrow][key] (wave-private)
        #pragma unroll
        for (int ct = 0; ct < 4; ct++) {
            float p0 = fexp2(st[ct][0]);
            float p1 = fexp2(st[ct][1]);
            float p2 = fexp2(st[ct][2]);
            float p3 = fexp2(st[ct][3]);
            l_part += (p0 + p1) + (p2 + p3);
            uint2v w; w.x = cvtpk(p0, p1); w.y = cvtpk(p2, p3);
            *(uint2v*)(pool + qrow * 72 + ct * 16 + quad * 4) = w;
        }
        // O += P V
        #pragma unroll
        for (int ks = 0; ks < 2; ks++) {
            short8 pf, vf[4];
            pf = *(const short8*)(pool + qrow * 72 + ks * 32 + quad * 8);
            #pragma unroll
            for (int dt = 0; dt < 4; dt++)
                vf[dt] = *(const short8*)(&Vs[cur][dt * 16 + lr][cc[ks]]);
            __builtin_amdgcn_s_setprio(1);
            #pragma unroll
            for (int dt = 0; dt < 4; dt++)
                oacc[dt] = __builtin_amdgcn_mfma_f32_16x16x32_bf16(pf, vf[dt], oacc[dt], 0, 0, 0);
            __builtin_amdgcn_s_setprio(0);
        }
        // hand tile t(it+1) to the next LDS buffer (compiler inserts this wave's vmcnt wait)
        if (it < 31) {
            int nxt = cur ^ 1;
            *(short8*)(&Ks[nxt][srow][scol]) = krH;
            *(short8*)(&Vs[nxt][srow][scol]) = vrH;
        }
        barrier_lgkm();   // ds_writes visible; global prefetch stays in flight
    };

    #pragma unroll 1
    for (int it2 = 0; it2 < 16; ++it2) {
        body(2 * it2,     0, krA, vrA, krB, vrB);
        body(2 * it2 + 1, 1, krB, vrB, krA, vrA);
    }

    // full-row l (replicated across quads after xor-reduce); fetch l for row quad*4+r via shfl
    float l = l_part;
    l += __shfl_xor(l, 16, 64);
    l += __shfl_xor(l, 32, 64);
    float linv[4];
    #pragma unroll
    for (int r = 0; r < 4; r++)
        linv[r] = 1.f / __shfl(l, quad * 4 + r, 64);
    // normalized bf16 O, direct aob store (row = q-row, col = h*64 + dt*16 + lr)
    #pragma unroll
    for (int dt = 0; dt < 4; dt++)
        #pragma unroll
        for (int r = 0; r < 4; r++) {
            int row = q0 + wave * 16 + quad * 4 + r;
            aob[((size_t)(b * 2048 + row)) * 1024 + h * 64 + dt * 16 + lr] =
                f2bf(oacc[dt][r] * linv[r]);
        }
}

// ---------------- launch ----------------
extern "C" void kernel_launch(void* const* d_in, const int* in_sizes, int n_in,
                              void* d_out, int out_size, void* d_ws, size_t ws_size,
                              hipStream_t stream) {
    const float* x     = (const float*)d_in[0];
    const float* emb   = (const float*)d_in[1];
    const float* gate  = (const float*)d_in[2];
    // d_in[3] crossattn_emb: unused by the reference
    const float* rope  = (const float*)d_in[4];
    const float* Wq1   = (const float*)d_in[5];
    const float* Wq2   = (const float*)d_in[6];
    const float* Wk1   = (const float*)d_in[7];
    const float* Wk2   = (const float*)d_in[8];
    const float* Wv    = (const float*)d_in[9];
    const float* Wo    = (const float*)d_in[10];
    const float* Wada1 = (const float*)d_in[11];
    const float* Wada2 = (const float*)d_in[12];
    const float* bada2 = (const float*)d_in[13];
    float* out = (float*)d_out;

    char* ws = (char*)d_ws;
    size_t off = 0;
    auto alloc = [&](size_t bytes) { void* p = ws + off; off += (bytes + 255) & ~(size_t)255; return p; };
    float* t_ada = (float*)alloc(2048 * 4);              // 8192 B
    float* ada   = (float*)alloc(4096 * 4);              // contiguous after t_ada (16384 B)
    float* cst   = (float*)alloc((size_t)131072 * 4);
    float* snt   = (float*)alloc((size_t)131072 * 4);
    u16* xn    = (u16*)alloc((size_t)4096 * 1024 * 2);
    u16* Wq1b  = (u16*)alloc((size_t)1024 * 1024 * 2);
    u16* Wk1b  = (u16*)alloc((size_t)1024 * 1024 * 2);
    u16* Wq2t  = (u16*)alloc((size_t)1024 * 1024 * 2);
    u16* Wk2t  = (u16*)alloc((size_t)1024 * 1024 * 2);
    u16* Wot   = (u16*)alloc((size_t)1024 * 1024 * 2);
    u16* WqkvT = (u16*)alloc((size_t)3072 * 1024 * 2);   // rows: WqeT | WkeT | WvT
    u16* qkvb  = (u16*)alloc((size_t)4096 * 2048 * 2);   // q|k (roped), row stride 2048
    u16* vtb   = (u16*)alloc((size_t)4096 * 1024 * 2);   // vt[bh][d][n]
    u16* aob   = (u16*)alloc((size_t)4096 * 1024 * 2);
    (void)ws_size; (void)in_sizes; (void)n_in; (void)out_size;

    // zero both atomic K-split targets in ONE memset (t_ada+ada contiguous)
    hipMemsetAsync(t_ada, 0, 24576, stream);

    // adaLN stage 1 (widened, atomics)
    k_ada1<<<dim3(16, 2, 8), 256, 0, stream>>>(emb, Wada1, t_ada);

    // prep: weight conversions + ada2 (atomics) + rope tables
    k_prep<<<dim3(16, 16, 8), 256, 0, stream>>>(Wq2, Wq2t, Wk2, Wk2t,
                                                Wv, WqkvT + (size_t)2048 * 1024, Wo, Wot,
                                                Wq1, Wq1b, Wk1, Wk1b,
                                                t_ada, Wada2, ada, rope, cst, snt);

    // LayerNorm + modulate (ada2 bias folded in)
    k_ln<<<4096, 256, 0, stream>>>(x, ada, bada2, xn);

    // fold stacked projections, 128x64 tiles, 512 threads (8 waves/block)
    gemm_fold<<<dim3(16, 8, 2), 512, 0, stream>>>(Wq2t, Wq1b, WqkvT,
                                                  Wk2t, Wk1b, WqkvT + (size_t)1024 * 1024);

    // fused QKV projection + rope epilogue + LDS-transposed V store (512 thr, 3 blocks/CU = 24 waves)
    gemm_bt<128, 128, 2, 4><<<dim3(24, 32), 512, 0, stream>>>(xn, WqkvT, qkvb, nullptr, vtb,
                                                              nullptr, nullptr, cst, snt, 2048, 1024);

    // flash attention: single launch, XCD-swizzled, lgkm-only body barrier
    k_attn<<<dim3(16, 32), 512, 0, stream>>>(qkvb, vtb, aob);

    // final projection + gated residual (512 thr, 2 blocks/CU = 16 waves)
    gemm_bt<128, 64, 1, 4><<<dim3(16, 32), 512, 0, stream>>>(aob, Wot, nullptr, out, nullptr, x, gate,
                                                             nullptr, nullptr, 1024, 1024);
}